// Round 13
// baseline (48.276 us; speedup 1.0000x reference)
//
#include <hip/hip_runtime.h>

// CumulativeFlattenedLinear: per-64-timestep-window projection (C=16 -> O=16,
// per-s weight slice, first ND=16 slots zero) + causal cumsum in window + bias.
//
// v13: structural instruction-count cut (the measured binder: v5 = ~17us VALU
// issue + latency; scans 192 instr, weight addressing ~250, staging ~130).
//  - v2 output mapping: lane = wg*16 + r covers window wg (of the wave's 4),
//    s = 4r..4r+3. One row_scan16 -> 4 outputs/lane: scan cost 192 -> ~60.
//  - Weights: contiguous float4 DIRECT from the original tensor:
//    w[o][c][4r..4r+3] = float4 at weight + o*768 + c*48 + (4r-16), 16B
//    aligned, L1-resident (48KB). No transpose, no LDS, no table. Discard
//    slots (r<4) via exec mask: skip loads+FMA, acc stays 0 (weight pad
//    equivalent), scan/store still executed by all lanes.
//  - x: direct coalesced dwordx4 global loads (1KB/wave-instr), consumed
//    per-c-chunk -> NO long-lived array > 32 regs (acc[4][4]=16 is max).
//    No LDS, no barriers anywhere.
//  - Wave owns o-quad wid*4..+3; block = 4 waves = all 16 o over 4 windows.
//  - Stores: float4, coalesced (v7 proved stores not the limiter; v8's
//    nontemporal disaster avoided -- normal stores).

#define CC 16
#define TT 131072
#define OO 16
#define NK 48
#define ND 16
#define GG 2048

// inclusive scan across each 16-lane DPP row (bound_ctrl=1 -> 0 shifted in).
// Verified numerically in R2 (v2 passed with this exact sequence).
__device__ __forceinline__ float row_scan16(float v) {
  int t;
  t = __builtin_amdgcn_update_dpp(0, __float_as_int(v), 0x111, 0xf, 0xf, true);
  v += __int_as_float(t);
  t = __builtin_amdgcn_update_dpp(0, __float_as_int(v), 0x112, 0xf, 0xf, true);
  v += __int_as_float(t);
  t = __builtin_amdgcn_update_dpp(0, __float_as_int(v), 0x114, 0xf, 0xf, true);
  v += __int_as_float(t);
  t = __builtin_amdgcn_update_dpp(0, __float_as_int(v), 0x118, 0xf, 0xf, true);
  v += __int_as_float(t);
  return v;
}

__global__ __launch_bounds__(256, 4) void cfl_kernel(
    const float* __restrict__ x, const float* __restrict__ weight,
    const float* __restrict__ bias, float* __restrict__ out) {
  const int tid = threadIdx.x;
  const int lane = tid & 63;
  const int wid = tid >> 6;        // wave id 0..3 -> o-quad
  const int wg = (lane >> 4);      // window-in-wave 0..3
  const int r = lane & 15;         // s-quad within window: s = 4r..4r+3

  const int blk = blockIdx.x;      // 4096 blocks; 512 per b-row (no straddle)
  const int b = blk >> 9;
  const int t0 = (blk & 511) * 256;
  const int tw = t0 + wg * 64 + 4 * r;  // this lane's first timestep

  const float* xb = x + (size_t)b * CC * TT;
  const int o0 = wid * 4;

  float acc[4][4];  // [oo][j] -- 16 regs, the largest live array
#pragma unroll
  for (int oo = 0; oo < 4; ++oo)
#pragma unroll
    for (int j = 0; j < 4; ++j) acc[oo][j] = 0.f;

  if (r >= 4) {  // r<4 are discard slots: projection is zero there
    const float* wb = weight + 4 * r - ND;  // lane-dependent, 16B aligned
#pragma unroll
    for (int c = 0; c < CC; ++c) {
      const float4 xc = *(const float4*)(xb + (size_t)c * TT + tw);
#pragma unroll
      for (int oo = 0; oo < 4; ++oo) {
        const float4 wc =
            *(const float4*)(wb + (o0 + oo) * (CC * NK) + c * NK);
        acc[oo][0] = fmaf(xc.x, wc.x, acc[oo][0]);
        acc[oo][1] = fmaf(xc.y, wc.y, acc[oo][1]);
        acc[oo][2] = fmaf(xc.z, wc.z, acc[oo][2]);
        acc[oo][3] = fmaf(xc.w, wc.w, acc[oo][3]);
      }
    }
  }

  float* ob = out + (size_t)b * OO * TT + tw;
#pragma unroll
  for (int oo = 0; oo < 4; ++oo) {
    // lane-local prefix over the 4 s-slots
    const float q0 = acc[oo][0];
    const float q1 = q0 + acc[oo][1];
    const float q2 = q1 + acc[oo][2];
    const float q3 = q2 + acc[oo][3];
    // window-wide inclusive scan of lane totals (16-lane row == window)
    const float inc = row_scan16(q3);
    const float ex = inc - q3 + bias[o0 + oo];
    const float4 res = make_float4(q0 + ex, q1 + ex, q2 + ex, q3 + ex);
    *(float4*)(ob + (size_t)(o0 + oo) * TT) = res;
  }
}

extern "C" void kernel_launch(void* const* d_in, const int* in_sizes, int n_in,
                              void* d_out, int out_size, void* d_ws, size_t ws_size,
                              hipStream_t stream) {
  const float* x = (const float*)d_in[0];
  const float* weight = (const float*)d_in[1];
  const float* bias = (const float*)d_in[2];
  float* out = (float*)d_out;

  // 16384 windows / 4 per block = 4096 blocks of 256 threads (4 waves x 4 o).
  cfl_kernel<<<4096, 256, 0, stream>>>(x, weight, bias, out);
}